// Round 3
// baseline (1298.477 us; speedup 1.0000x reference)
//
#include <hip/hip_runtime.h>
#include <hip/hip_bf16.h>

#define EPS_BN 1e-5f

constexpr int BATCH = 16, NPOINT = 4096, NSAMP = 32;
constexpr int NROWS  = BATCH * NPOINT * NSAMP;   // 2,097,152
constexpr int NEWX_ELEMS = BATCH * NPOINT * 3;   // 196,608

// d_ws float layout (folded weights: BN absorbed into W', b')
constexpr int W0_OFF = 0;      // 64*3
constexpr int B0_OFF = 192;    // 64
constexpr int W1_OFF = 256;    // 64*64
constexpr int B1_OFF = 4352;   // 64
constexpr int W2_OFF = 4416;   // 128*64
constexpr int B2_OFF = 12608;  // 128

__device__ __forceinline__ void fold_layer(
    const float* __restrict__ w,  const float* __restrict__ b,
    const float* __restrict__ g,  const float* __restrict__ be,
    const float* __restrict__ m,  const float* __restrict__ v,
    int cin, int cout, float* __restrict__ Wf, float* __restrict__ bf, int t, int nt)
{
    for (int o = t; o < cout; o += nt) {
        float s = g[o] * rsqrtf(v[o] + EPS_BN);
        bf[o] = (b[o] - m[o]) * s + be[o];
    }
    for (int i = t; i < cout * cin; i += nt) {
        int o = i / cin;
        float s = g[o] * rsqrtf(v[o] + EPS_BN);
        Wf[i] = w[i] * s;
    }
}

__global__ void fold_kernel(
    const float* w0, const float* b0, const float* g0,
    const float* be0, const float* m0, const float* v0,
    const float* w1, const float* b1, const float* g1,
    const float* be1, const float* m1, const float* v1,
    const float* w2, const float* b2, const float* g2,
    const float* be2, const float* m2, const float* v2,
    float* __restrict__ ws)
{
    int t = threadIdx.x;
    fold_layer(w0, b0, g0, be0, m0, v0, 3,  64,  ws + W0_OFF, ws + B0_OFF, t, 256);
    fold_layer(w1, b1, g1, be1, m1, v1, 64, 64,  ws + W1_OFF, ws + B1_OFF, t, 256);
    fold_layer(w2, b2, g2, be2, m2, v2, 64, 128, ws + W2_OFF, ws + B2_OFF, t, 256);
}

// new_x passthrough, f32 -> f32: 196,608 floats = 49,152 float4
__global__ void copy_new_x(const float4* __restrict__ in, float4* __restrict__ out)
{
    int i = blockIdx.x * 256 + threadIdx.x;   // i < 49,152
    out[i] = in[i];
}

// Per-thread: one point-sample row. h1 constant-indexed registers; h2
// (produced in a dynamic channel loop) round-trips through LDS as f32,
// stride 65 floats per row -> bank (tid+j)%32, 2-way aliasing (free).
#define STRIDE_H2 65

__global__ __launch_bounds__(256, 2) void sa_main_kernel(
    const float* __restrict__ xg,
    const float* __restrict__ ws,
    float* __restrict__ feats)
{
    __shared__ float h2lds[256 * STRIDE_H2];   // 66,560 B

    const int tid = threadIdx.x;
    const int Rg  = blockIdx.x * 256 + tid;          // global row (< 2,097,152)
    const int g   = Rg >> 5;                          // group (b*P+p)
    const int s   = tid & 31;                         // sample index within group

    // ---- layer 0: x[3] -> h1[64] (registers, fully unrolled) ----
    const float* xp = xg + (size_t)Rg * 3;
    const float x0 = xp[0], x1 = xp[1], x2 = xp[2];

    const float* __restrict__ W0 = ws + W0_OFF;
    const float* __restrict__ B0 = ws + B0_OFF;
    float h1[64];
#pragma unroll
    for (int o = 0; o < 64; ++o) {
        float a = fmaf(x2, W0[o * 3 + 2],
                  fmaf(x1, W0[o * 3 + 1],
                  fmaf(x0, W0[o * 3 + 0], B0[o])));
        h1[o] = fmaxf(a, 0.0f);
    }

    // ---- layer 1: h1[64] -> h2[64], dynamic o-loop, f32 to LDS ----
    const float* __restrict__ W1 = ws + W1_OFF;
    const float* __restrict__ B1 = ws + B1_OFF;
    float* hrow = &h2lds[tid * STRIDE_H2];
#pragma unroll 1
    for (int ob = 0; ob < 32; ++ob) {
        const int o0 = 2 * ob;
        float a0 = B1[o0], a1 = B1[o0 + 1];
#pragma unroll
        for (int c = 0; c < 64; ++c) {
            a0 = fmaf(h1[c], W1[(o0    ) * 64 + c], a0);
            a1 = fmaf(h1[c], W1[(o0 + 1) * 64 + c], a1);
        }
        hrow[o0]     = fmaxf(a0, 0.0f);
        hrow[o0 + 1] = fmaxf(a1, 0.0f);
    }

    // ---- read h2 back into constant-indexed registers ----
    float h2r[64];
#pragma unroll
    for (int j = 0; j < 64; ++j)
        h2r[j] = hrow[j];

    // ---- layer 2 + max over s: h2[64] -> 128 ch, shuffle-max over 32 lanes ----
    const float* __restrict__ W2 = ws + W2_OFF;
    const float* __restrict__ B2 = ws + B2_OFF;
    float* outp = feats + (size_t)g * 128;

#pragma unroll 1
    for (int ob = 0; ob < 4; ++ob) {
        float mine = 0.0f;
#pragma unroll 1
        for (int oi = 0; oi < 32; ++oi) {
            const int o = ob * 32 + oi;
            float a = B2[o];
#pragma unroll
            for (int c = 0; c < 64; ++c)
                a = fmaf(h2r[c], W2[o * 64 + c], a);
            a = fmaxf(a, 0.0f);
#pragma unroll
            for (int d = 16; d > 0; d >>= 1)
                a = fmaxf(a, __shfl_xor(a, d, 32));
            if (oi == s)
                mine = a;
        }
        // lane s holds channel ob*32+s of its group -> coalesced 128B per group
        outp[ob * 32 + s] = mine;
    }
}

extern "C" void kernel_launch(void* const* d_in, const int* in_sizes, int n_in,
                              void* d_out, int out_size, void* d_ws, size_t ws_size,
                              hipStream_t stream)
{
    const float* xg   = (const float*)d_in[0];
    const float* newx = (const float*)d_in[1];
    const float *W[3], *Bb[3], *G[3], *Be[3], *M[3], *V[3];
    for (int l = 0; l < 3; ++l) {
        W[l]  = (const float*)d_in[2 + 6 * l + 0];
        Bb[l] = (const float*)d_in[2 + 6 * l + 1];
        G[l]  = (const float*)d_in[2 + 6 * l + 2];
        Be[l] = (const float*)d_in[2 + 6 * l + 3];
        M[l]  = (const float*)d_in[2 + 6 * l + 4];
        V[l]  = (const float*)d_in[2 + 6 * l + 5];
    }

    float* wsf = (float*)d_ws;

    fold_kernel<<<1, 256, 0, stream>>>(
        W[0], Bb[0], G[0], Be[0], M[0], V[0],
        W[1], Bb[1], G[1], Be[1], M[1], V[1],
        W[2], Bb[2], G[2], Be[2], M[2], V[2], wsf);

    copy_new_x<<<192, 256, 0, stream>>>((const float4*)newx, (float4*)d_out);

    float* feats = (float*)d_out + NEWX_ELEMS;
    sa_main_kernel<<<NROWS / 256, 256, 0, stream>>>(xg, wsf, feats);
}

// Round 4
// 139.034 us; speedup vs baseline: 9.3393x; 9.3393x over previous
//
#include <hip/hip_runtime.h>
#include <hip/hip_bf16.h>

#define EPS_BN 1e-5f

typedef __attribute__((ext_vector_type(8))) short short8;   // 8 x bf16 (4 VGPR)
typedef __attribute__((ext_vector_type(4))) float float4v;  // MFMA acc

constexpr int NGROUPS    = 65536;     // B*P = 16*4096
constexpr int NEWX_ELEMS = 196608;    // B*P*3
constexpr int GRID       = 2048;      // blocks of 256 (4 waves); 8192 waves
constexpr int GITER      = NGROUPS / (GRID * 4);  // 8 groups per wave

// d_ws layout: f32 indices for folded f32 data, byte offsets for bf16 weights
constexpr int W0F = 0;      // f32[192]  W0' (64x3)
constexpr int B0F = 192;    // f32[64]
constexpr int B1F = 256;    // f32[64]
constexpr int B2F = 320;    // f32[128]
constexpr int W1B = 1792;   // bytes: ushort[4096]  W1' (64x64) bf16
constexpr int W2B = 10240;  // bytes: ushort[8192]  W2' (128x64) bf16

__device__ __forceinline__ unsigned short f2bf(float x) {
    return __builtin_bit_cast(unsigned short, __float2bfloat16(x));
}
__device__ __forceinline__ unsigned packbf(float a, float b) {
    return ((unsigned)f2bf(b) << 16) | (unsigned)f2bf(a);
}

__global__ void fold_kernel(
    const float* w0, const float* b0, const float* g0,
    const float* be0, const float* m0, const float* v0,
    const float* w1, const float* b1, const float* g1,
    const float* be1, const float* m1, const float* v1,
    const float* w2, const float* b2, const float* g2,
    const float* be2, const float* m2, const float* v2,
    float* __restrict__ ws)
{
    const int t = threadIdx.x;
    ushort* w1b = (ushort*)((char*)ws + W1B);
    ushort* w2b = (ushort*)((char*)ws + W2B);
    if (t < 64) {
        float s0 = g0[t] * rsqrtf(v0[t] + EPS_BN);
        ws[B0F + t] = (b0[t] - m0[t]) * s0 + be0[t];
        ws[W0F + t*3 + 0] = w0[t*3 + 0] * s0;
        ws[W0F + t*3 + 1] = w0[t*3 + 1] * s0;
        ws[W0F + t*3 + 2] = w0[t*3 + 2] * s0;
        float s1 = g1[t] * rsqrtf(v1[t] + EPS_BN);
        ws[B1F + t] = (b1[t] - m1[t]) * s1 + be1[t];
    }
    if (t < 128) {
        float s2 = g2[t] * rsqrtf(v2[t] + EPS_BN);
        ws[B2F + t] = (b2[t] - m2[t]) * s2 + be2[t];
    }
    for (int i = t; i < 64*64; i += 256) {
        int o = i >> 6;
        float s = g1[o] * rsqrtf(v1[o] + EPS_BN);
        w1b[i] = f2bf(w1[i] * s);
    }
    for (int i = t; i < 128*64; i += 256) {
        int o = i >> 6;
        float s = g2[o] * rsqrtf(v2[o] + EPS_BN);
        w2b[i] = f2bf(w2[i] * s);
    }
}

// new_x passthrough, f32 -> f32
__global__ void copy_new_x(const float4* __restrict__ in, float4* __restrict__ out)
{
    int i = blockIdx.x * 256 + threadIdx.x;   // < 49,152
    out[i] = in[i];
}

// One wave = one group (32 samples). No barriers; per-wave LDS h-tiles
// [32 rows][64 ch] bf16, XOR-swizzled (idx ^= (r&7)<<3 in ushort units) so
// b64 writes are ~2-way and ds_read_b128 fragment reads are conflict-free.
// Layers 0/1 use swapped-operand MFMA (D[o][r] -> contiguous channel writes);
// layer 2 unswapped (D[r][o] -> cheap max-over-samples epilogue).
__global__ __launch_bounds__(256, 2) void sa_mfma_kernel(
    const float* __restrict__ xg,
    const float* __restrict__ wsf,
    float* __restrict__ feats)
{
    __shared__ __align__(16) ushort H1s[4][2048];   // 4 waves x 4KB
    __shared__ __align__(16) ushort H2s[4][2048];

    const int tid = threadIdx.x;
    const int w   = tid >> 6;
    const int l   = tid & 63;
    const int l15 = l & 15;
    const int lhi = l >> 4;

    ushort* H1 = H1s[w];
    ushort* H2 = H2s[w];
    const ushort* w1b = (const ushort*)((const char*)wsf + W1B);
    const ushort* w2b = (const ushort*)((const char*)wsf + W2B);

    const short8  zero8 = {0,0,0,0,0,0,0,0};
    const float4v zero4 = {0.f, 0.f, 0.f, 0.f};

    // ---- hoisted weight fragments (per-wave, loop-invariant) ----
    // layer0 A-frag: row o = 16mt+l15, k-slots 8*lhi+j; data only k<4:
    // {w0,w1,w2,b0} at lanes lhi==0, bias via k=3 (x-frag supplies 1.0 there).
    short8 b0f[4];
#pragma unroll
    for (int mt = 0; mt < 4; ++mt) {
        union { short8 v; unsigned d[4]; } f;
        f.v = zero8;
        if (lhi == 0) {
            int o = 16*mt + l15;
            f.d[0] = packbf(wsf[W0F + o*3 + 0], wsf[W0F + o*3 + 1]);
            f.d[1] = packbf(wsf[W0F + o*3 + 2], wsf[B0F + o]);
        }
        b0f[mt] = f.v;
    }
    // W' stored [cout][cin] row-major bf16: frag = 16B at [16t+l15]*64 + 32ks + 8lhi
    short8 b1f[2][4];
#pragma unroll
    for (int ks = 0; ks < 2; ++ks)
#pragma unroll
        for (int mt = 0; mt < 4; ++mt)
            b1f[ks][mt] = *(const short8*)&w1b[(16*mt + l15)*64 + 32*ks + 8*lhi];
    short8 b2f[2][8];
#pragma unroll
    for (int ks = 0; ks < 2; ++ks)
#pragma unroll
        for (int nt = 0; nt < 8; ++nt)
            b2f[ks][nt] = *(const short8*)&w2b[(16*nt + l15)*64 + 32*ks + 8*lhi];

    float4v b1vv[4];   // bias for h2 channels o = 16mt + 4lhi + i
#pragma unroll
    for (int mt = 0; mt < 4; ++mt)
        b1vv[mt] = *(const float4v*)&wsf[B1F + 16*mt + 4*lhi];
    float b2v[8];      // bias for output channels 16n + l15
#pragma unroll
    for (int n = 0; n < 8; ++n)
        b2v[n] = wsf[B2F + 16*n + l15];

    const int wid = blockIdx.x * 4 + w;

#pragma unroll 1
    for (int it = 0; it < GITER; ++it) {
        const int g = wid + it * (GRID * 4);

        // ---- x fragments (B-operand): col r = 16nt+l15, k<4 = {x0,x1,x2,1} ----
        short8 xf[2];
#pragma unroll
        for (int nt = 0; nt < 2; ++nt) {
            union { short8 v; unsigned d[4]; } f;
            f.v = zero8;
            if (lhi == 0) {
                const float* xp = xg + ((size_t)g*32 + 16*nt + l15) * 3;
                f.d[0] = packbf(xp[0], xp[1]);
                f.d[1] = packbf(xp[2], 1.0f);
            }
            xf[nt] = f.v;
        }

        // ---- layer 0 (swapped): D[o][r]; relu; contiguous b64 writes -> H1 ----
#pragma unroll
        for (int nt = 0; nt < 2; ++nt) {
            const int r = 16*nt + l15;
            const int swz = (r & 7) << 3;
#pragma unroll
            for (int mt = 0; mt < 4; ++mt) {
                float4v d = __builtin_amdgcn_mfma_f32_16x16x32_bf16(
                                b0f[mt], xf[nt], zero4, 0, 0, 0);
                uint2 p;
                p.x = packbf(fmaxf(d[0], 0.f), fmaxf(d[1], 0.f));
                p.y = packbf(fmaxf(d[2], 0.f), fmaxf(d[3], 0.f));
                *(uint2*)&H1[(r*64 + 16*mt + 4*lhi) ^ swz] = p;
            }
        }

        // ---- layer 1 (swapped): B-frags from H1; bias+relu; -> H2 ----
        short8 h1f[2][2];
#pragma unroll
        for (int nt = 0; nt < 2; ++nt) {
            const int r = 16*nt + l15;
            const int swz = (r & 7) << 3;
#pragma unroll
            for (int ks = 0; ks < 2; ++ks)
                h1f[nt][ks] = *(const short8*)&H1[(r*64 + 32*ks + 8*lhi) ^ swz];
        }
#pragma unroll
        for (int nt = 0; nt < 2; ++nt) {
            const int r = 16*nt + l15;
            const int swz = (r & 7) << 3;
#pragma unroll
            for (int mt = 0; mt < 4; ++mt) {
                float4v a = __builtin_amdgcn_mfma_f32_16x16x32_bf16(
                                b1f[0][mt], h1f[nt][0], zero4, 0, 0, 0);
                a = __builtin_amdgcn_mfma_f32_16x16x32_bf16(
                                b1f[1][mt], h1f[nt][1], a, 0, 0, 0);
                uint2 p;
                p.x = packbf(fmaxf(a[0] + b1vv[mt][0], 0.f),
                             fmaxf(a[1] + b1vv[mt][1], 0.f));
                p.y = packbf(fmaxf(a[2] + b1vv[mt][2], 0.f),
                             fmaxf(a[3] + b1vv[mt][3], 0.f));
                *(uint2*)&H2[(r*64 + 16*mt + 4*lhi) ^ swz] = p;
            }
        }

        // ---- layer 2 (unswapped): A-frags from H2; max over 32 samples ----
        short8 a2[2][2];
#pragma unroll
        for (int m = 0; m < 2; ++m) {
            const int r = 16*m + l15;
            const int swz = (r & 7) << 3;
#pragma unroll
            for (int ks = 0; ks < 2; ++ks)
                a2[m][ks] = *(const short8*)&H2[(r*64 + 32*ks + 8*lhi) ^ swz];
        }
        float* outp = feats + (size_t)g * 128;
#pragma unroll
        for (int n = 0; n < 8; ++n) {
            float4v c0 = __builtin_amdgcn_mfma_f32_16x16x32_bf16(
                             a2[0][0], b2f[0][n], zero4, 0, 0, 0);
            c0 = __builtin_amdgcn_mfma_f32_16x16x32_bf16(
                             a2[0][1], b2f[1][n], c0, 0, 0, 0);
            float4v c1 = __builtin_amdgcn_mfma_f32_16x16x32_bf16(
                             a2[1][0], b2f[0][n], zero4, 0, 0, 0);
            c1 = __builtin_amdgcn_mfma_f32_16x16x32_bf16(
                             a2[1][1], b2f[1][n], c1, 0, 0, 0);
            // max over rows: 8 in-lane + lanes {l, l^16, l^32}
            float v = fmaxf(fmaxf(fmaxf(c0[0], c0[1]), fmaxf(c0[2], c0[3])),
                            fmaxf(fmaxf(c1[0], c1[1]), fmaxf(c1[2], c1[3])));
            v = fmaxf(v, __shfl_xor(v, 16, 64));
            v = fmaxf(v, __shfl_xor(v, 32, 64));
            if (l < 16)
                outp[16*n + l15] = fmaxf(v + b2v[n], 0.f);   // bias+relu after max
        }
    }
}

extern "C" void kernel_launch(void* const* d_in, const int* in_sizes, int n_in,
                              void* d_out, int out_size, void* d_ws, size_t ws_size,
                              hipStream_t stream)
{
    const float* xg   = (const float*)d_in[0];
    const float* newx = (const float*)d_in[1];
    const float *W[3], *Bb[3], *G[3], *Be[3], *M[3], *V[3];
    for (int ll = 0; ll < 3; ++ll) {
        W[ll]  = (const float*)d_in[2 + 6*ll + 0];
        Bb[ll] = (const float*)d_in[2 + 6*ll + 1];
        G[ll]  = (const float*)d_in[2 + 6*ll + 2];
        Be[ll] = (const float*)d_in[2 + 6*ll + 3];
        M[ll]  = (const float*)d_in[2 + 6*ll + 4];
        V[ll]  = (const float*)d_in[2 + 6*ll + 5];
    }

    float* wsf = (float*)d_ws;

    fold_kernel<<<1, 256, 0, stream>>>(
        W[0], Bb[0], G[0], Be[0], M[0], V[0],
        W[1], Bb[1], G[1], Be[1], M[1], V[1],
        W[2], Bb[2], G[2], Be[2], M[2], V[2], wsf);

    copy_new_x<<<192, 256, 0, stream>>>((const float4*)newx, (float4*)d_out);

    float* feats = (float*)d_out + NEWX_ELEMS;
    sa_mfma_kernel<<<GRID, 256, 0, stream>>>(xg, wsf, feats);
}